// Round 12
// baseline (28.265 us; speedup 1.0000x reference)
//
#include <hip/hip_runtime.h>
#include <hip/hip_bf16.h>
#include <math.h>

#define N_ATOMS 1024
#define IN_F 64
#define H_DIM 32
#define NRBF 50
#define TILE 16
#define NT 64
#define NBT 2080
#define TBL 1024              // f16 G-table rows (64 KB)
#define SASTR 40              // sA row stride in f16 elems (80B: 16B-aligned, banks spread 8-wide)
#define HSTR 36               // hp-tile LDS row stride in f16 elems (72B)

typedef _Float16 f16x8 __attribute__((ext_vector_type(8)));
typedef _Float16 f16x2 __attribute__((ext_vector_type(2)));
typedef float    f32x4 __attribute__((ext_vector_type(4)));
typedef unsigned short ushort4v __attribute__((ext_vector_type(4)));

// ---- Kernel 1 (58 blocks): hp(f16), G table(f16), tt, W1 frags(f16), bw ----
__global__ __launch_bounds__(256) void prep_kernel(
    const float* __restrict__ h, const float* __restrict__ W_fc,
    const float* __restrict__ W_edge, const float* __restrict__ means,
    const float* __restrict__ betas, const float* __restrict__ W1,
    const float* __restrict__ b1, const float* __restrict__ W2,
    _Float16* __restrict__ hp, _Float16* __restrict__ Gb,
    _Float16* __restrict__ Wp, float2* __restrict__ bw,
    int* __restrict__ tt)
{
    const int blk = blockIdx.x;
    const int t = threadIdx.x;
    if (blk < 32) {                        // hp = h @ W_fc, 4 outputs/thread
        int id = blk * 256 + t;
        int i  = id >> 3;
        int o4 = (id & 7) * 4;
        f32x4 acc = {0.f, 0.f, 0.f, 0.f};
        #pragma unroll 8
        for (int k = 0; k < IN_F; ++k) {
            const float hv = h[i * IN_F + k];
            const float4 wv = *(const float4*)&W_fc[k * H_DIM + o4];
            acc[0] += hv * wv.x; acc[1] += hv * wv.y;
            acc[2] += hv * wv.z; acc[3] += hv * wv.w;
        }
        _Float16 o0 = (_Float16)acc[0], o1 = (_Float16)acc[1];
        _Float16 o2 = (_Float16)acc[2], o3 = (_Float16)acc[3];
        _Float16* dst = hp + i * H_DIM + o4;
        dst[0] = o0; dst[1] = o1; dst[2] = o2; dst[3] = o3;
    } else if (blk < 48) {                 // G table, window-truncated k-loop
        int id = (blk - 32) * 256 + t;
        int idx = id >> 2, c0 = (id & 3) * 8;
        const float m0   = means[0];
        const float dm   = means[1] - means[0];
        const float beta = betas[0];       // all betas equal by construction
        float ed = (float)idx * (1.0f / (float)(TBL - 1));
        int kc = (int)((ed - m0) / dm + 0.5f);
        kc = kc < 0 ? 0 : (kc > NRBF - 1 ? NRBF - 1 : kc);
        int k0 = kc - 9 < 0 ? 0 : kc - 9;
        int k1 = kc + 9 > NRBF - 1 ? NRBF - 1 : kc + 9;
        float acc[8];
        #pragma unroll
        for (int c = 0; c < 8; ++c) acc[c] = 0.f;
        for (int k = k0; k <= k1; ++k) {   // <=19 terms; rest < 1e-9
            float d = ed - (m0 + (float)k * dm);
            float wv = __expf(-beta * d * d);
            const float4 wa = *(const float4*)&W_edge[k * H_DIM + c0];
            const float4 wb = *(const float4*)&W_edge[k * H_DIM + c0 + 4];
            acc[0] += wv * wa.x; acc[1] += wv * wa.y;
            acc[2] += wv * wa.z; acc[3] += wv * wa.w;
            acc[4] += wv * wb.x; acc[5] += wv * wb.y;
            acc[6] += wv * wb.z; acc[7] += wv * wb.w;
        }
        f16x8 pk;
        #pragma unroll
        for (int c = 0; c < 8; ++c) pk[c] = (_Float16)acc[c];
        *(f16x8*)&Gb[idx * H_DIM + c0] = pk;
    } else if (blk < 57) {                 // triangular tile table
        int e = (blk - 48) * 256 + t;
        if (e < NBT) {
            int ti = (int)(64.5f - sqrtf(64.5f * 64.5f - 2.0f * (float)e));
            ti = ti < 0 ? 0 : (ti > NT - 1 ? NT - 1 : ti);
            while ((ti + 1) * NT - ((ti + 1) * ti) / 2 <= e) ++ti;
            while (ti > 0 && ti * NT - (ti * (ti - 1)) / 2 > e) --ti;
            int tj = ti + (e - (ti * NT - (ti * (ti - 1)) / 2));
            tt[e] = (ti << 8) | tj;
        }
    } else {                               // W1 fragments (f16) + bw
        #pragma unroll
        for (int q = 0; q < 4; ++q) {
            int f  = t * 4 + q;            // f = ct*512 + lane*8 + j
            int ct = f >> 9, ln = (f >> 3) & 63, j = f & 7;
            int c0f = ln & 15, kb = (ln >> 4) * 8;
            Wp[f] = (_Float16)W1[(kb + j) * H_DIM + c0f + 16 * ct];
        }
        if (t < 32) { float2 v; v.x = b1[t]; v.y = W2[t]; bw[t] = v; }
    }
}

// ---- Kernel 2: one 16x16 pair tile per block, packed-f16 cnorm pipeline ----
__global__ __launch_bounds__(256, 6) void pair_kernel(
    const float* __restrict__ x, const _Float16* __restrict__ hp,
    const _Float16* __restrict__ Gb, const _Float16* __restrict__ Wp,
    const float2* __restrict__ bw, const int* __restrict__ tt,
    float* __restrict__ partials)
{
    __shared__ _Float16 shpi[TILE * HSTR], shpj[TILE * HSTR];
    __shared__ _Float16 sA[256 * SASTR];
    __shared__ float swave[4];

    const int t    = threadIdx.x;
    const int lane = t & 63;
    const int w    = t >> 6;
    const int c0f  = lane & 15;
    const int kb   = (lane >> 4) * 8;
    const int b    = blockIdx.x;

    const int tv = tt[b];                  // uniform -> s_load
    const int ti = tv >> 8, tj = tv & 255;
    const int i0 = ti * TILE, j0 = tj * TILE;
    const float wgt = (ti == tj) ? 1.0f : 2.0f;

    const int li = t >> 4;
    const int lj = t & 15;

    // x coords direct from global (L1-hot), issues immediately
    const float xi0 = x[(i0 + li) * 3 + 0];
    const float xi1 = x[(i0 + li) * 3 + 1];
    const float xi2 = x[(i0 + li) * 3 + 2];
    const float xj0 = x[(j0 + lj) * 3 + 0];
    const float xj1 = x[(j0 + lj) * 3 + 1];
    const float xj2 = x[(j0 + lj) * 3 + 2];

    // stage hp tiles (f16): threads 0..127, one 16B chunk each
    if (t < 64) {
        int r = t >> 2, c = t & 3;
        *(f16x8*)&shpi[r * HSTR + c * 8] = *(const f16x8*)&hp[(i0 + r) * H_DIM + c * 8];
    } else if (t < 128) {
        int u = t - 64, r = u >> 2, c = u & 3;
        *(f16x8*)&shpj[r * HSTR + c * 8] = *(const f16x8*)&hp[(j0 + r) * H_DIM + c * 8];
    }

    // pre-packed W1 fragments (f16) + bias/W2
    const f16x8 bfrag0 = *(const f16x8*)&Wp[lane * 8];
    const f16x8 bfrag1 = *(const f16x8*)&Wp[512 + lane * 8];
    const float2 bw0 = bw[c0f];
    const float2 bw1 = bw[c0f + 16];

    // distance / cutoff / table index
    const float dx = xj0 - xi0, dy = xj1 - xi1, dz = xj2 - xi2;
    const float s  = dx * dx + dy * dy + dz * dz;
    const float dist = s + 1e-8f;
    const float dn2  = s / (s + 1e-8f);              // exactly 0 on diagonal
    const float sn   = __sinf(0.62831853f * dist);
    const float K    = dn2 * (sn * sn) * (sn * sn);  // dn2 * cut^2
    const float ed   = __expf(-dist);

    float uu = ed * (float)(TBL - 1);
    int idx  = (int)(uu + 0.5f);
    if (idx > TBL - 1) idx = TBL - 1;
    const _Float16* __restrict__ r0 = Gb + idx * H_DIM;
    const f16x8 g0 = *(const f16x8*)(r0);
    const f16x8 g1 = *(const f16x8*)(r0 + 8);
    const f16x8 g2 = *(const f16x8*)(r0 + 16);
    const f16x8 g3 = *(const f16x8*)(r0 + 24);

    const _Float16 kh = (_Float16)K;
    const f16x8 kv = {kh, kh, kh, kh, kh, kh, kh, kh};

    __syncthreads();                       // hp tiles visible

    // cnorm = ((hp_i+hp_j)*g)^2 * K, all packed f16, straight into sA
    const _Float16* rowi = &shpi[li * HSTR];
    const _Float16* rowj = &shpj[lj * HSTR];
    {
        const f16x8 e0 = *(const f16x8*)(rowi)      + *(const f16x8*)(rowj);
        const f16x8 e1 = *(const f16x8*)(rowi + 8)  + *(const f16x8*)(rowj + 8);
        const f16x8 e2 = *(const f16x8*)(rowi + 16) + *(const f16x8*)(rowj + 16);
        const f16x8 e3 = *(const f16x8*)(rowi + 24) + *(const f16x8*)(rowj + 24);
        const f16x8 t0 = e0 * g0, t1 = e1 * g1, t2 = e2 * g2, t3 = e3 * g3;
        *(f16x8*)&sA[t * SASTR]      = t0 * t0 * kv;
        *(f16x8*)&sA[t * SASTR + 8]  = t1 * t1 * kv;
        *(f16x8*)&sA[t * SASTR + 16] = t2 * t2 * kv;
        *(f16x8*)&sA[t * SASTR + 24] = t3 * t3 * kv;
    }
    __syncthreads();

    // MFMA: a = cnorm @ W1 ; epilogue sigmoid/W2
    float p = 0.f;
    #pragma unroll
    for (int rt = 0; rt < 4; ++rt) {
        const int row = w * 64 + rt * 16 + c0f;
        const f16x8 afrag = *(const f16x8*)&sA[row * SASTR + kb];
        f32x4 acc0 = {0.f, 0.f, 0.f, 0.f};
        acc0 = __builtin_amdgcn_mfma_f32_16x16x32_f16(afrag, bfrag0, acc0, 0, 0, 0);
        f32x4 acc1 = {0.f, 0.f, 0.f, 0.f};
        acc1 = __builtin_amdgcn_mfma_f32_16x16x32_f16(afrag, bfrag1, acc1, 0, 0, 0);
        #pragma unroll
        for (int r = 0; r < 4; ++r) {
            p += bw0.y * __builtin_amdgcn_rcpf(1.0f + __expf(-(acc0[r] + bw0.x)));
            p += bw1.y * __builtin_amdgcn_rcpf(1.0f + __expf(-(acc1[r] + bw1.x)));
        }
    }

    // block reduction (deterministic)
    float v = wgt * p;
    #pragma unroll
    for (int off = 32; off > 0; off >>= 1)
        v += __shfl_down(v, off);
    if (lane == 0) swave[w] = v;
    __syncthreads();
    if (t == 0)
        partials[b] = (swave[0] + swave[1]) + (swave[2] + swave[3]);
}

// ---- Kernel 3: final deterministic reduction -------------------------------
__global__ __launch_bounds__(256) void reduce_kernel(
    const float* __restrict__ partials, const float* __restrict__ b2,
    float* __restrict__ out)
{
    __shared__ float sm[256];
    const int t = threadIdx.x;
    float a = 0.f;
    for (int u = t; u < NBT; u += 256) a += partials[u];
    sm[t] = a;
    __syncthreads();
    for (int off = 128; off > 0; off >>= 1) {
        if (t < off) sm[t] += sm[t + off];
        __syncthreads();
    }
    if (t == 0)
        out[0] = sm[0] + (float)N_ATOMS * (float)N_ATOMS * b2[0];
}

extern "C" void kernel_launch(void* const* d_in, const int* in_sizes, int n_in,
                              void* d_out, int out_size, void* d_ws, size_t ws_size,
                              hipStream_t stream) {
    const float* h      = (const float*)d_in[0];
    const float* x      = (const float*)d_in[1];
    const float* W_fc   = (const float*)d_in[2];
    const float* W_edge = (const float*)d_in[3];
    const float* means  = (const float*)d_in[4];
    const float* betas  = (const float*)d_in[5];
    const float* W1     = (const float*)d_in[6];
    const float* b1     = (const float*)d_in[7];
    const float* W2     = (const float*)d_in[8];
    const float* b2     = (const float*)d_in[9];
    float* out = (float*)d_out;

    char* base = (char*)d_ws;
    float*     ws_partials = (float*)base;                 // 2080 f @0 (pad 10240)
    _Float16*  ws_hp       = (_Float16*)(base + 10240);    // 32768 f16 (64KB)
    _Float16*  ws_Gb       = (_Float16*)(base + 75776);    // 1024*32 f16 (64KB)
    _Float16*  ws_Wp       = (_Float16*)(base + 141312);   // 1024 f16 (2KB)
    float2*    ws_bw       = (float2*)(base + 143360);     // 32 float2
    int*       ws_tt       = (int*)(base + 143616);        // 2080 int

    prep_kernel<<<58, 256, 0, stream>>>(h, W_fc, W_edge, means, betas,
                                        W1, b1, W2, ws_hp, ws_Gb, ws_Wp,
                                        ws_bw, ws_tt);
    pair_kernel<<<NBT, 256, 0, stream>>>(x, ws_hp, ws_Gb, ws_Wp, ws_bw,
                                         ws_tt, ws_partials);
    reduce_kernel<<<1, 256, 0, stream>>>(ws_partials, b2, out);
}